// Round 9
// baseline (492.635 us; speedup 1.0000x reference)
//
#include <hip/hip_runtime.h>
#include <math.h>

#define NSTEPS 256
#define GRIDN  160
#define NVOX   (160 * 160 * 160)
#define NTPA   20                  // tiles per axis (8^3-voxel tiles)
#define NTILES (NTPA * NTPA * NTPA)
#define NSHARD 8                   // cursor shards (by blockIdx&7 == XCD heuristic)
#define NBIN3  512                 // 8x8x8 coarse LOR bins
#define ITEM_CAP (3 * 1024 * 1024)

#define INV_SIGMA 0.05233333f      // 2.355/45 (weight/predicate only)

struct LorT { float4 a; float4 b; };   // a: p0.xyz, tof ; b: d.xyz, L

// ---- strict voxel path (contract OFF: bit-match f32 numpy floor decisions) ----
__device__ __forceinline__ bool sample_vox(
    int j, float p0x, float p0y, float p0z,
    float dx, float dy, float dz, float L, float s_tof,
    int& ix, int& iy, int& iz, float& e)
{
#pragma clang fp contract(off)
    const float t = (j + 0.5f) * (1.0f / 256.0f);
    const float px = p0x + t * dx;
    const float py = p0y + t * dy;
    const float pz = p0z + t * dz;
    const float fx = floorf((px + 160.0f) * 0.5f);
    const float fy = floorf((py + 160.0f) * 0.5f);
    const float fz = floorf((pz + 160.0f) * 0.5f);
    const bool inb = (fx >= 0.0f) & (fx < 160.0f) &
                     (fy >= 0.0f) & (fy < 160.0f) &
                     (fz >= 0.0f) & (fz < 160.0f);
    const float s = (t - 0.5f) * L;
    const float u = (s - s_tof) * INV_SIGMA;
    e = 0.5f * (u * u);
    if (inb & (e < 10.0f)) {
        ix = (int)fx; iy = (int)fy; iz = (int)fz;
        return true;
    }
    return false;
}

__device__ __forceinline__ void lor_window(
    float p0x, float p0y, float p0z, float dx, float dy, float dz,
    float L, float s_tof, int& j0, int& j1)
{
#pragma clang fp contract(off)
    const float SIGMA = (float)(45.0 / 2.355);
    const float CUTS  = 4.4721360f * SIGMA;      // e<10 support
    const float invL = 1.0f / L;
    float t0 = 0.5f + (s_tof - CUTS) * invL;
    float t1 = 0.5f + (s_tof + CUTS) * invL;
    if (t0 > t1) { const float tmp = t0; t0 = t1; t1 = tmp; }
    const float pc[3] = {p0x, p0y, p0z};
    const float dc[3] = {dx, dy, dz};
    #pragma unroll
    for (int a = 0; a < 3; ++a) {
        if (dc[a] != 0.0f) {
            const float inv = 1.0f / dc[a];
            const float ta = (-160.0f - pc[a]) * inv;
            const float tb = ( 160.0f - pc[a]) * inv;
            t0 = fmaxf(t0, fminf(ta, tb));
            t1 = fminf(t1, fmaxf(ta, tb));
        } else if (pc[a] < -160.0f || pc[a] >= 160.0f) t1 = -1.0f;
    }
    t0 = fmaxf(t0, 0.0f);
    t1 = fminf(t1, 1.0f);
    j0 = (int)floorf(t0 * 256.0f - 0.5f) - 2;
    j1 = (int)ceilf (t1 * 256.0f - 0.5f) + 2;
    if (!(t0 <= t1)) { j0 = 0; j1 = -1; }
    j0 = max(j0, 0);
    j1 = min(j1, NSTEPS - 1);
}

// ---- coarse LOR binning by TOF-window center (L2 locality for forward) ----
__global__ __launch_bounds__(256) void bin_count_kernel(
    const float* __restrict__ lors, int* __restrict__ binh,
    int* __restrict__ binidx, int n)
{
    const int i = blockIdx.x * blockDim.x + threadIdx.x;
    if (i >= n) return;
    const float* l = lors + (size_t)i * 7;
    const float p0x = l[0], p0y = l[1], p0z = l[2];
    const float dx = l[3] - p0x, dy = l[4] - p0y, dz = l[5] - p0z;
    const float L = sqrtf(dx * dx + dy * dy + dz * dz);
    float tc = 0.5f + (l[6] * 0.15f) / L;
    if (!(tc >= 0.0f)) tc = 0.0f;
    if (tc > 1.0f)     tc = 1.0f;
    int bx = (int)floorf((p0x + tc * dx + 160.0f) * 0.025f); bx = min(max(bx, 0), 7);
    int by = (int)floorf((p0y + tc * dy + 160.0f) * 0.025f); by = min(max(by, 0), 7);
    int bz = (int)floorf((p0z + tc * dz + 160.0f) * 0.025f); bz = min(max(bz, 0), 7);
    const int b = (bx << 6) | (by << 3) | bz;
    binidx[i] = b;
    atomicAdd(&binh[b], 1);
}

__global__ __launch_bounds__(512) void bin_scan_kernel(
    const int* __restrict__ binh, int* __restrict__ binc)
{
    __shared__ int tmp[NBIN3];
    const int t = threadIdx.x;
    tmp[t] = binh[t];
    __syncthreads();
    for (int off = 1; off < NBIN3; off <<= 1) {
        int v = 0;
        if (t >= off) v = tmp[t - off];
        __syncthreads();
        tmp[t] += v;
        __syncthreads();
    }
    binc[t] = tmp[t] - binh[t];
}

__global__ __launch_bounds__(256) void reorder_kernel(
    const float* __restrict__ lors, const int* __restrict__ binidx,
    int* __restrict__ binc, LorT* __restrict__ lortab, int n)
{
#pragma clang fp contract(off)
    const int i = blockIdx.x * blockDim.x + threadIdx.x;
    if (i >= n) return;
    const int slot = atomicAdd(&binc[binidx[i]], 1);
    const float* l = lors + (size_t)i * 7;
    const float p0x = l[0], p0y = l[1], p0z = l[2];
    const float dx = l[3] - p0x, dy = l[4] - p0y, dz = l[5] - p0z;
    const float L = sqrtf(dx * dx + dy * dy + dz * dz);
    lortab[slot].a = make_float4(p0x, p0y, p0z, l[6]);
    lortab[slot].b = make_float4(dx, dy, dz, L);
}

// ---- forward + run count (fused emit0): wave per sorted LOR, XCD-chunked ----
__global__ __launch_bounds__(256) void forward_count_kernel(
    const float* __restrict__ image, const LorT* __restrict__ lortab,
    float* __restrict__ p, int* __restrict__ win, int* __restrict__ hist,
    int n, int chunk)
{
#pragma clang fp contract(off)
    const int v    = threadIdx.x >> 6;
    const int lane = threadIdx.x & 63;
    const int shard = blockIdx.x & 7;
    const int ci = ((int)(blockIdx.x >> 3)) * 4 + v;
    if (ci >= chunk) return;
    const int i = shard * chunk + ci;
    if (i >= n) return;

    const float4 A = lortab[i].a, B = lortab[i].b;
    const float p0x = A.x, p0y = A.y, p0z = A.z, tof = A.w;
    const float dx = B.x, dy = B.y, dz = B.z, L = B.w;
    const float dl = L * (1.0f / 256.0f);
    const float s_tof = tof * 0.15f;

    int j0, j1;
    lor_window(p0x, p0y, p0z, dx, dy, dz, L, s_tof, j0, j1);
    if (lane == 0) win[i] = j0 | (j1 << 8);        // j1=-1 survives (arith >>)
    const int nk = (j1 - j0 + 64) >> 6;
    if (nk <= 0) { if (lane == 0) p[i] = 0.0f; return; }

    float psum = 0.0f;
    for (int k = 0; k < nk; ++k) {
        const int j = j0 + lane + (k << 6);
        int ix, iy, iz; float e;
        const bool valid = (j <= j1) &&
            sample_vox(j, p0x, p0y, p0z, dx, dy, dz, L, s_tof, ix, iy, iz, e);
        if (valid)
            psum += image[ix * 25600 + iy * 160 + iz] * (__expf(-e) * dl);
        const unsigned key = valid
            ? (unsigned)((ix >> 3) * 400 + (iy >> 3) * 20 + (iz >> 3))
            : 0xFFFFFFFFu;
        const unsigned prev = __shfl_up(key, 1, 64);
        const bool chg = (lane == 0) || (prev != key);
        if (chg && valid)
            atomicAdd(&hist[(int)key * NSHARD + shard], 1);
    }
    #pragma unroll
    for (int off = 32; off >= 1; off >>= 1)
        psum += __shfl_xor(psum, off, 64);
    if (lane == 0) p[i] = psum;
}

// ---- exclusive scan over NTILES*NSHARD bins (single block, two sweeps) ----
__global__ __launch_bounds__(1024) void scan_kernel(
    const int* __restrict__ hist, int* __restrict__ offs, int* __restrict__ cursor)
{
    __shared__ int part[1024];
    const int NB = NTILES * NSHARD;        // 64000
    const int t = threadIdx.x;
    const int base = t * 64;
    int s = 0;
    for (int i = 0; i < 64; ++i) {
        const int b = base + i;
        if (b < NB) s += hist[b];
    }
    part[t] = s;
    __syncthreads();
    for (int off = 1; off < 1024; off <<= 1) {
        int v = 0;
        if (t >= off) v = part[t - off];
        __syncthreads();
        part[t] += v;
        __syncthreads();
    }
    int running = (t > 0) ? part[t - 1] : 0;
    for (int i = 0; i < 64; ++i) {
        const int b = base + i;
        if (b < NB) {
            offs[b] = running;
            cursor[b] = running;
            running += hist[b];
        }
    }
    if (t == 1023) offs[NB] = part[1023];
}

// ---- emit fill: same grid/mapping as forward (shard must match!) ----
__global__ __launch_bounds__(256) void emit_fill_kernel(
    const LorT* __restrict__ lortab, const int* __restrict__ win,
    int* __restrict__ cursor, unsigned* __restrict__ items,
    int n, int chunk)
{
#pragma clang fp contract(off)
    const int v    = threadIdx.x >> 6;
    const int lane = threadIdx.x & 63;
    const int shard = blockIdx.x & 7;
    const int ci = ((int)(blockIdx.x >> 3)) * 4 + v;
    if (ci >= chunk) return;
    const int i = shard * chunk + ci;
    if (i >= n) return;

    const int wv = win[i];
    const int j0 = wv & 255;
    const int j1 = wv >> 8;
    const int nk = (j1 - j0 + 64) >> 6;
    if (nk <= 0) return;

    const float4 A = lortab[i].a, B = lortab[i].b;
    const float p0x = A.x, p0y = A.y, p0z = A.z;
    const float dx = B.x, dy = B.y, dz = B.z, L = B.w;
    const float s_tof = A.w * 0.15f;

    for (int k = 0; k < nk; ++k) {
        const int j = j0 + lane + (k << 6);
        int ix, iy, iz; float e;
        const bool valid = (j <= j1) &&
            sample_vox(j, p0x, p0y, p0z, dx, dy, dz, L, s_tof, ix, iy, iz, e);
        const unsigned key = valid
            ? (unsigned)((ix >> 3) * 400 + (iy >> 3) * 20 + (iz >> 3))
            : 0xFFFFFFFFu;
        const unsigned prev = __shfl_up(key, 1, 64);
        const bool chg = (lane == 0) || (prev != key);
        const unsigned long long cm = __ballot(chg);
        if (chg && valid) {
            const unsigned long long above = cm & ~((2ULL << lane) - 1ULL);
            const int nxt = above ? (__ffsll((unsigned long long)above) - 1) : 64;
            const int len = nxt - lane;
            const int slot = atomicAdd(&cursor[(int)key * NSHARD + shard], 1);
            if (slot < ITEM_CAP)
                items[slot] = ((unsigned)i << 14) | ((unsigned)j << 6)
                            | (unsigned)(len - 1);
        }
    }
}

// ---- tileB (fused finalize): LDS bp tile, out = image/(eff+eps)*bp ----
__global__ __launch_bounds__(256) void tileB_kernel(
    const float* __restrict__ image, const float* __restrict__ effmap,
    const LorT* __restrict__ lortab, const int* __restrict__ offs,
    const unsigned* __restrict__ items, const float* __restrict__ p,
    float* __restrict__ out)
{
    const int b = blockIdx.x;
    const int i0 = offs[b * NSHARD], i1 = min(offs[b * NSHARD + NSHARD], ITEM_CAP);
    if (i0 >= i1) return;                 // uncovered tile: out stays 0 (memset)
    const int tx0 = (b / 400) << 3, ty0 = ((b / 20) % 20) << 3, tz0 = (b % 20) << 3;
    __shared__ float acc[512];
    const int t = threadIdx.x;
    for (int v = t; v < 512; v += 256) acc[v] = 0.0f;
    __syncthreads();
    for (int idx = i0 + t; idx < i1; idx += 256) {
        const unsigned it = items[idx];
        const int lor = (int)(it >> 14);
        const int js  = (int)((it >> 6) & 255);
        const int len = (int)(it & 63) + 1;
        const float4 A = lortab[lor].a, B = lortab[lor].b;
        const float dl = B.w * (1.0f / 256.0f);
        const float s_tof = A.w * 0.15f;
        const float pv = p[lor];
        for (int m = 0; m < len; ++m) {
            int ix, iy, iz; float e;
            if (sample_vox(js + m, A.x, A.y, A.z, B.x, B.y, B.z, B.w, s_tof,
                           ix, iy, iz, e)) {
                const int lx = ix - tx0, ly = iy - ty0, lz = iz - tz0;
                if ((unsigned)lx < 8u && (unsigned)ly < 8u && (unsigned)lz < 8u)
                    atomicAdd(&acc[(lx << 6) | (ly << 3) | lz],
                              pv * (__expf(-e) * dl));
            }
        }
    }
    __syncthreads();
    for (int v = t; v < 512; v += 256) {
        const int lx = v >> 6, ly = (v >> 3) & 7, lz = v & 7;
        const size_t g = (size_t)(tx0 + lx) * 25600 + (ty0 + ly) * 160 + (tz0 + lz);
        out[g] = image[g] / (effmap[g] + 1e-8f) * acc[v];
    }
}

// ---- fallback: direct trace with global atomics + separate finalize ----
__global__ __launch_bounds__(256) void trace_direct_kernel(
    const float* __restrict__ image, const float* __restrict__ lors,
    float* __restrict__ bp, int n_lors)
{
#pragma clang fp contract(off)
    const int wave = (int)((blockIdx.x * blockDim.x + threadIdx.x) >> 6);
    const int lane = threadIdx.x & 63;
    if (wave >= n_lors) return;
    const float* l = lors + (size_t)wave * 7;
    const float p0x = l[0], p0y = l[1], p0z = l[2];
    const float dx = l[3] - p0x, dy = l[4] - p0y, dz = l[5] - p0z;
    const float tof = l[6];
    const float L  = sqrtf(dx * dx + dy * dy + dz * dz);
    const float dl = L * (1.0f / 256.0f);
    const float s_tof = tof * 0.15f;
    int j0, j1;
    lor_window(p0x, p0y, p0z, dx, dy, dz, L, s_tof, j0, j1);
    const int nk = (j1 - j0 + 64) >> 6;
    if (nk <= 0) return;
    int flat[4]; float w[4]; float psum = 0.0f;
    for (int k = 0; k < nk; ++k) {
        const int j = j0 + lane + (k << 6);
        int ix, iy, iz; float e; float wk = 0.0f; int fl = 0;
        if (j <= j1 &&
            sample_vox(j, p0x, p0y, p0z, dx, dy, dz, L, s_tof, ix, iy, iz, e)) {
            wk = __expf(-e) * dl;
            fl = ix * 25600 + iy * 160 + iz;
            psum += image[fl] * wk;
        }
        flat[k] = fl; w[k] = wk;
    }
    #pragma unroll
    for (int off = 32; off >= 1; off >>= 1) psum += __shfl_xor(psum, off, 64);
    for (int k = 0; k < nk; ++k)
        if (w[k] > 0.0f) atomicAdd(&bp[flat[k]], psum * w[k]);
}

__global__ __launch_bounds__(256) void finalize_kernel(
    const float4* __restrict__ image, const float4* __restrict__ effmap,
    float4* __restrict__ out, int n4)
{
    const int i = blockIdx.x * blockDim.x + threadIdx.x;
    if (i >= n4) return;
    const float4 im = image[i];
    const float4 ef = effmap[i];
    float4 b = out[i];
    b.x = im.x / (ef.x + 1e-8f) * b.x;
    b.y = im.y / (ef.y + 1e-8f) * b.y;
    b.z = im.z / (ef.z + 1e-8f) * b.z;
    b.w = im.w / (ef.w + 1e-8f) * b.w;
    out[i] = b;
}

extern "C" void kernel_launch(void* const* d_in, const int* in_sizes, int n_in,
                              void* d_out, int out_size, void* d_ws, size_t ws_size,
                              hipStream_t stream) {
    const float* image  = (const float*)d_in[0];
    const float* effmap = (const float*)d_in[1];
    const float* lors   = (const float*)d_in[2];
    float* out = (float*)d_out;
    const int n = in_sizes[2] / 7;

    // ws layout (256-aligned regions)
    char* ws = (char*)d_ws;
    const size_t binh_off   = 0;                               // 512*4
    const size_t binc_off   = 2048;                            // 512*4
    const size_t hist_off   = 4096;                            // 64000*4
    const size_t offs_off   = hist_off + 256256;               // 64001*4
    const size_t cursor_off = offs_off + 256256;               // 64000*4
    const size_t p_off      = cursor_off + 256256;
    const size_t win_off    = p_off    + (((size_t)n * 4 + 255) & ~(size_t)255);
    const size_t binidx_off = win_off  + (((size_t)n * 4 + 255) & ~(size_t)255);
    const size_t lortab_off = binidx_off + (((size_t)n * 4 + 255) & ~(size_t)255);
    const size_t items_off  = lortab_off + (size_t)n * sizeof(LorT);
    const size_t total      = items_off + (size_t)ITEM_CAP * 4;

    hipMemsetAsync(out, 0, (size_t)NVOX * sizeof(float), stream);

    if (ws_size >= total && n < (1 << 17)) {
        int*      binh   = (int*)(ws + binh_off);
        int*      binc   = (int*)(ws + binc_off);
        int*      hist   = (int*)(ws + hist_off);
        int*      offs   = (int*)(ws + offs_off);
        int*      cursor = (int*)(ws + cursor_off);
        float*    p      = (float*)(ws + p_off);
        int*      win    = (int*)(ws + win_off);
        int*      binidx = (int*)(ws + binidx_off);
        LorT*     lortab = (LorT*)(ws + lortab_off);
        unsigned* items  = (unsigned*)(ws + items_off);

        // zero binh + (pad) + hist in one shot
        hipMemsetAsync(ws, 0, hist_off + 256256, stream);

        const int tb = (n + 255) / 256;
        bin_count_kernel<<<tb, 256, 0, stream>>>(lors, binh, binidx, n);
        bin_scan_kernel<<<1, 512, 0, stream>>>(binh, binc);
        reorder_kernel<<<tb, 256, 0, stream>>>(lors, binidx, binc, lortab, n);

        const int chunk = (n + 7) / 8;
        const int Bc = (chunk + 3) / 4;          // 4 waves/block
        forward_count_kernel<<<8 * Bc, 256, 0, stream>>>(
            image, lortab, p, win, hist, n, chunk);
        scan_kernel<<<1, 1024, 0, stream>>>(hist, offs, cursor);
        emit_fill_kernel<<<8 * Bc, 256, 0, stream>>>(
            lortab, win, cursor, items, n, chunk);
        tileB_kernel<<<NTILES, 256, 0, stream>>>(
            image, effmap, lortab, offs, items, p, out);
    } else {
        trace_direct_kernel<<<(n + 3) / 4, 256, 0, stream>>>(image, lors, out, n);
        const int n4 = NVOX / 4;
        finalize_kernel<<<(n4 + 255) / 256, 256, 0, stream>>>(
            (const float4*)image, (const float4*)effmap, (float4*)out, n4);
    }
}

// Round 10
// 465.353 us; speedup vs baseline: 1.0586x; 1.0586x over previous
//
#include <hip/hip_runtime.h>
#include <math.h>

#define NSTEPS 256
#define GRIDN  160
#define NVOX   (160 * 160 * 160)
#define NTPA   20                  // tiles per axis (8^3-voxel tiles)
#define NTILES (NTPA * NTPA * NTPA)
#define NSHARD 8                   // cursor shards (shard-major: no cross-XCD lines)
#define NB     (NTILES * NSHARD)   // 64000
#define NBIN3  512                 // 8x8x8 coarse LOR bins
#define ITEM_CAP (3 * 1024 * 1024)

#define INV_SIGMA 0.05233333f      // 2.355/45 (weight/predicate only)

struct LorT { float4 a; float4 b; };   // a: p0.xyz, tof ; b: d.xyz, L

// ---- strict voxel path (contract OFF: bit-match f32 numpy floor decisions) ----
__device__ __forceinline__ bool sample_vox(
    int j, float p0x, float p0y, float p0z,
    float dx, float dy, float dz, float L, float s_tof,
    int& ix, int& iy, int& iz, float& e)
{
#pragma clang fp contract(off)
    const float t = (j + 0.5f) * (1.0f / 256.0f);
    const float px = p0x + t * dx;
    const float py = p0y + t * dy;
    const float pz = p0z + t * dz;
    const float fx = floorf((px + 160.0f) * 0.5f);
    const float fy = floorf((py + 160.0f) * 0.5f);
    const float fz = floorf((pz + 160.0f) * 0.5f);
    const bool inb = (fx >= 0.0f) & (fx < 160.0f) &
                     (fy >= 0.0f) & (fy < 160.0f) &
                     (fz >= 0.0f) & (fz < 160.0f);
    const float s = (t - 0.5f) * L;
    const float u = (s - s_tof) * INV_SIGMA;
    e = 0.5f * (u * u);
    if (inb & (e < 10.0f)) {
        ix = (int)fx; iy = (int)fy; iz = (int)fz;
        return true;
    }
    return false;
}

__device__ __forceinline__ void lor_window(
    float p0x, float p0y, float p0z, float dx, float dy, float dz,
    float L, float s_tof, int& j0, int& j1)
{
#pragma clang fp contract(off)
    const float SIGMA = (float)(45.0 / 2.355);
    const float CUTS  = 4.4721360f * SIGMA;      // e<10 support
    const float invL = 1.0f / L;
    float t0 = 0.5f + (s_tof - CUTS) * invL;
    float t1 = 0.5f + (s_tof + CUTS) * invL;
    if (t0 > t1) { const float tmp = t0; t0 = t1; t1 = tmp; }
    const float pc[3] = {p0x, p0y, p0z};
    const float dc[3] = {dx, dy, dz};
    #pragma unroll
    for (int a = 0; a < 3; ++a) {
        if (dc[a] != 0.0f) {
            const float inv = 1.0f / dc[a];
            const float ta = (-160.0f - pc[a]) * inv;
            const float tb = ( 160.0f - pc[a]) * inv;
            t0 = fmaxf(t0, fminf(ta, tb));
            t1 = fminf(t1, fmaxf(ta, tb));
        } else if (pc[a] < -160.0f || pc[a] >= 160.0f) t1 = -1.0f;
    }
    t0 = fmaxf(t0, 0.0f);
    t1 = fminf(t1, 1.0f);
    j0 = (int)floorf(t0 * 256.0f - 0.5f) - 2;
    j1 = (int)ceilf (t1 * 256.0f - 0.5f) + 2;
    if (!(t0 <= t1)) { j0 = 0; j1 = -1; }
    j0 = max(j0, 0);
    j1 = min(j1, NSTEPS - 1);
}

// ---- coarse LOR binning by TOF-window center (L2 locality for forward) ----
__global__ __launch_bounds__(256) void bin_count_kernel(
    const float* __restrict__ lors, int* __restrict__ binh,
    int* __restrict__ binidx, int n)
{
    const int i = blockIdx.x * blockDim.x + threadIdx.x;
    if (i >= n) return;
    const float* l = lors + (size_t)i * 7;
    const float p0x = l[0], p0y = l[1], p0z = l[2];
    const float dx = l[3] - p0x, dy = l[4] - p0y, dz = l[5] - p0z;
    const float L = sqrtf(dx * dx + dy * dy + dz * dz);
    float tc = 0.5f + (l[6] * 0.15f) / L;
    if (!(tc >= 0.0f)) tc = 0.0f;
    if (tc > 1.0f)     tc = 1.0f;
    int bx = (int)floorf((p0x + tc * dx + 160.0f) * 0.025f); bx = min(max(bx, 0), 7);
    int by = (int)floorf((p0y + tc * dy + 160.0f) * 0.025f); by = min(max(by, 0), 7);
    int bz = (int)floorf((p0z + tc * dz + 160.0f) * 0.025f); bz = min(max(bz, 0), 7);
    const int b = (bx << 6) | (by << 3) | bz;
    binidx[i] = b;
    atomicAdd(&binh[b], 1);
}

__global__ __launch_bounds__(512) void bin_scan_kernel(
    const int* __restrict__ binh, int* __restrict__ binc)
{
    __shared__ int tmp[NBIN3];
    const int t = threadIdx.x;
    tmp[t] = binh[t];
    __syncthreads();
    for (int off = 1; off < NBIN3; off <<= 1) {
        int v = 0;
        if (t >= off) v = tmp[t - off];
        __syncthreads();
        tmp[t] += v;
        __syncthreads();
    }
    binc[t] = tmp[t] - binh[t];
}

__global__ __launch_bounds__(256) void reorder_kernel(
    const float* __restrict__ lors, const int* __restrict__ binidx,
    int* __restrict__ binc, LorT* __restrict__ lortab, int n)
{
#pragma clang fp contract(off)
    const int i = blockIdx.x * blockDim.x + threadIdx.x;
    if (i >= n) return;
    const int slot = atomicAdd(&binc[binidx[i]], 1);
    const float* l = lors + (size_t)i * 7;
    const float p0x = l[0], p0y = l[1], p0z = l[2];
    const float dx = l[3] - p0x, dy = l[4] - p0y, dz = l[5] - p0z;
    const float L = sqrtf(dx * dx + dy * dy + dz * dz);
    lortab[slot].a = make_float4(p0x, p0y, p0z, l[6]);
    lortab[slot].b = make_float4(dx, dy, dz, L);
}

// ---- forward + run count (fused emit0): wave per sorted LOR, XCD-chunked ----
__global__ __launch_bounds__(256) void forward_count_kernel(
    const float* __restrict__ image, const LorT* __restrict__ lortab,
    float* __restrict__ p, int* __restrict__ win, int* __restrict__ hist,
    int n, int chunk)
{
#pragma clang fp contract(off)
    const int v    = threadIdx.x >> 6;
    const int lane = threadIdx.x & 63;
    const int shard = blockIdx.x & 7;
    const int ci = ((int)(blockIdx.x >> 3)) * 4 + v;
    if (ci >= chunk) return;
    const int i = shard * chunk + ci;
    if (i >= n) return;

    const float4 A = lortab[i].a, B = lortab[i].b;
    const float p0x = A.x, p0y = A.y, p0z = A.z, tof = A.w;
    const float dx = B.x, dy = B.y, dz = B.z, L = B.w;
    const float dl = L * (1.0f / 256.0f);
    const float s_tof = tof * 0.15f;

    int j0, j1;
    lor_window(p0x, p0y, p0z, dx, dy, dz, L, s_tof, j0, j1);
    if (lane == 0) win[i] = j0 | (j1 << 8);        // j1=-1 survives (arith >>)
    const int nk = (j1 - j0 + 64) >> 6;
    if (nk <= 0) { if (lane == 0) p[i] = 0.0f; return; }

    int* histS = hist + shard * NTILES;            // shard-major: XCD-private region
    float psum = 0.0f;
    for (int k = 0; k < nk; ++k) {
        const int j = j0 + lane + (k << 6);
        int ix, iy, iz; float e;
        const bool valid = (j <= j1) &&
            sample_vox(j, p0x, p0y, p0z, dx, dy, dz, L, s_tof, ix, iy, iz, e);
        if (valid)
            psum += image[ix * 25600 + iy * 160 + iz] * (__expf(-e) * dl);
        const unsigned key = valid
            ? (unsigned)((ix >> 3) * 400 + (iy >> 3) * 20 + (iz >> 3))
            : 0xFFFFFFFFu;
        const unsigned prev = __shfl_up(key, 1, 64);
        const bool chg = (lane == 0) || (prev != key);
        if (chg && valid)
            atomicAdd(&histS[(int)key], 1);
    }
    #pragma unroll
    for (int off = 32; off >= 1; off >>= 1)
        psum += __shfl_xor(psum, off, 64);
    if (lane == 0) p[i] = psum;
}

// ---- hierarchical exclusive scan over NB=64000 (125 blocks x 512) ----
__global__ __launch_bounds__(512) void scanA_kernel(
    const int* __restrict__ hist, int* __restrict__ offs, int* __restrict__ blksum)
{
    __shared__ int tmp[512];
    const int t = threadIdx.x;
    const int b = blockIdx.x * 512 + t;
    const int v = hist[b];
    tmp[t] = v;
    __syncthreads();
    for (int off = 1; off < 512; off <<= 1) {
        int u = 0;
        if (t >= off) u = tmp[t - off];
        __syncthreads();
        tmp[t] += u;
        __syncthreads();
    }
    offs[b] = tmp[t] - v;                 // local exclusive
    if (t == 511) blksum[blockIdx.x] = tmp[511];
}

__global__ __launch_bounds__(128) void scanB_kernel(int* __restrict__ blksum)
{
    __shared__ int tmp[128];
    const int t = threadIdx.x;
    const int v = (t < 125) ? blksum[t] : 0;
    tmp[t] = v;
    __syncthreads();
    for (int off = 1; off < 128; off <<= 1) {
        int u = 0;
        if (t >= off) u = tmp[t - off];
        __syncthreads();
        tmp[t] += u;
        __syncthreads();
    }
    if (t < 125) blksum[t] = tmp[t] - v;  // exclusive block offsets
    if (t == 127) blksum[125] = tmp[127]; // grand total
}

__global__ __launch_bounds__(512) void scanC_kernel(
    int* __restrict__ offs, int* __restrict__ cursor, const int* __restrict__ blksum)
{
    const int t = threadIdx.x;
    const int b = blockIdx.x * 512 + t;
    const int o = offs[b] + blksum[blockIdx.x];
    offs[b] = o;
    cursor[b] = o;
    if (b == 0) offs[NB] = blksum[125];
}

// ---- emit fill: same grid/mapping as forward (shard must match!) ----
__global__ __launch_bounds__(256) void emit_fill_kernel(
    const LorT* __restrict__ lortab, const int* __restrict__ win,
    int* __restrict__ cursor, unsigned* __restrict__ items,
    int n, int chunk)
{
#pragma clang fp contract(off)
    const int v    = threadIdx.x >> 6;
    const int lane = threadIdx.x & 63;
    const int shard = blockIdx.x & 7;
    const int ci = ((int)(blockIdx.x >> 3)) * 4 + v;
    if (ci >= chunk) return;
    const int i = shard * chunk + ci;
    if (i >= n) return;

    const int wv = win[i];
    const int j0 = wv & 255;
    const int j1 = wv >> 8;
    const int nk = (j1 - j0 + 64) >> 6;
    if (nk <= 0) return;

    const float4 A = lortab[i].a, B = lortab[i].b;
    const float p0x = A.x, p0y = A.y, p0z = A.z;
    const float dx = B.x, dy = B.y, dz = B.z, L = B.w;
    const float s_tof = A.w * 0.15f;

    int* curS = cursor + shard * NTILES;           // shard-major

    for (int k = 0; k < nk; ++k) {
        const int j = j0 + lane + (k << 6);
        int ix, iy, iz; float e;
        const bool valid = (j <= j1) &&
            sample_vox(j, p0x, p0y, p0z, dx, dy, dz, L, s_tof, ix, iy, iz, e);
        const unsigned key = valid
            ? (unsigned)((ix >> 3) * 400 + (iy >> 3) * 20 + (iz >> 3))
            : 0xFFFFFFFFu;
        const unsigned prev = __shfl_up(key, 1, 64);
        const bool chg = (lane == 0) || (prev != key);
        const unsigned long long cm = __ballot(chg);
        if (chg && valid) {
            const unsigned long long above = cm & ~((2ULL << lane) - 1ULL);
            const int nxt = above ? (__ffsll((unsigned long long)above) - 1) : 64;
            const int len = nxt - lane;
            const int slot = atomicAdd(&curS[(int)key], 1);
            if (slot < ITEM_CAP)
                items[slot] = ((unsigned)i << 14) | ((unsigned)j << 6)
                            | (unsigned)(len - 1);
        }
    }
}

// ---- tileB (fused finalize): LDS bp tile, out = image/(eff+eps)*bp ----
__global__ __launch_bounds__(256) void tileB_kernel(
    const float* __restrict__ image, const float* __restrict__ effmap,
    const LorT* __restrict__ lortab, const int* __restrict__ offs,
    const unsigned* __restrict__ items, const float* __restrict__ p,
    float* __restrict__ out)
{
    const int b = blockIdx.x;
    // shard-major segments: [offs[s*NTILES+b], offs[s*NTILES+b+1]) for s=0..7
    int s0[NSHARD], s1[NSHARD]; int tot = 0;
    #pragma unroll
    for (int s = 0; s < NSHARD; ++s) {
        s0[s] = offs[s * NTILES + b];
        s1[s] = min(offs[s * NTILES + b + 1], ITEM_CAP);
        tot += max(s1[s] - s0[s], 0);
    }
    if (tot == 0) return;                 // uncovered tile: out stays 0 (memset)
    const int tx0 = (b / 400) << 3, ty0 = ((b / 20) % 20) << 3, tz0 = (b % 20) << 3;
    __shared__ float acc[512];
    const int t = threadIdx.x;
    for (int v = t; v < 512; v += 256) acc[v] = 0.0f;
    __syncthreads();
    for (int s = 0; s < NSHARD; ++s) {
        for (int idx = s0[s] + t; idx < s1[s]; idx += 256) {
            const unsigned it = items[idx];
            const int lor = (int)(it >> 14);
            const int js  = (int)((it >> 6) & 255);
            const int len = (int)(it & 63) + 1;
            const float4 A = lortab[lor].a, B = lortab[lor].b;
            const float dl = B.w * (1.0f / 256.0f);
            const float s_tof = A.w * 0.15f;
            const float pv = p[lor];
            for (int m = 0; m < len; ++m) {
                int ix, iy, iz; float e;
                if (sample_vox(js + m, A.x, A.y, A.z, B.x, B.y, B.z, B.w, s_tof,
                               ix, iy, iz, e)) {
                    const int lx = ix - tx0, ly = iy - ty0, lz = iz - tz0;
                    if ((unsigned)lx < 8u && (unsigned)ly < 8u && (unsigned)lz < 8u)
                        atomicAdd(&acc[(lx << 6) | (ly << 3) | lz],
                                  pv * (__expf(-e) * dl));
                }
            }
        }
    }
    __syncthreads();
    for (int v = t; v < 512; v += 256) {
        const int lx = v >> 6, ly = (v >> 3) & 7, lz = v & 7;
        const size_t g = (size_t)(tx0 + lx) * 25600 + (ty0 + ly) * 160 + (tz0 + lz);
        out[g] = image[g] / (effmap[g] + 1e-8f) * acc[v];
    }
}

// ---- fallback: direct trace with global atomics + separate finalize ----
__global__ __launch_bounds__(256) void trace_direct_kernel(
    const float* __restrict__ image, const float* __restrict__ lors,
    float* __restrict__ bp, int n_lors)
{
#pragma clang fp contract(off)
    const int wave = (int)((blockIdx.x * blockDim.x + threadIdx.x) >> 6);
    const int lane = threadIdx.x & 63;
    if (wave >= n_lors) return;
    const float* l = lors + (size_t)wave * 7;
    const float p0x = l[0], p0y = l[1], p0z = l[2];
    const float dx = l[3] - p0x, dy = l[4] - p0y, dz = l[5] - p0z;
    const float tof = l[6];
    const float L  = sqrtf(dx * dx + dy * dy + dz * dz);
    const float dl = L * (1.0f / 256.0f);
    const float s_tof = tof * 0.15f;
    int j0, j1;
    lor_window(p0x, p0y, p0z, dx, dy, dz, L, s_tof, j0, j1);
    const int nk = (j1 - j0 + 64) >> 6;
    if (nk <= 0) return;
    int flat[4]; float w[4]; float psum = 0.0f;
    for (int k = 0; k < nk; ++k) {
        const int j = j0 + lane + (k << 6);
        int ix, iy, iz; float e; float wk = 0.0f; int fl = 0;
        if (j <= j1 &&
            sample_vox(j, p0x, p0y, p0z, dx, dy, dz, L, s_tof, ix, iy, iz, e)) {
            wk = __expf(-e) * dl;
            fl = ix * 25600 + iy * 160 + iz;
            psum += image[fl] * wk;
        }
        flat[k] = fl; w[k] = wk;
    }
    #pragma unroll
    for (int off = 32; off >= 1; off >>= 1) psum += __shfl_xor(psum, off, 64);
    for (int k = 0; k < nk; ++k)
        if (w[k] > 0.0f) atomicAdd(&bp[flat[k]], psum * w[k]);
}

__global__ __launch_bounds__(256) void finalize_kernel(
    const float4* __restrict__ image, const float4* __restrict__ effmap,
    float4* __restrict__ out, int n4)
{
    const int i = blockIdx.x * blockDim.x + threadIdx.x;
    if (i >= n4) return;
    const float4 im = image[i];
    const float4 ef = effmap[i];
    float4 b = out[i];
    b.x = im.x / (ef.x + 1e-8f) * b.x;
    b.y = im.y / (ef.y + 1e-8f) * b.y;
    b.z = im.z / (ef.z + 1e-8f) * b.z;
    b.w = im.w / (ef.w + 1e-8f) * b.w;
    out[i] = b;
}

extern "C" void kernel_launch(void* const* d_in, const int* in_sizes, int n_in,
                              void* d_out, int out_size, void* d_ws, size_t ws_size,
                              hipStream_t stream) {
    const float* image  = (const float*)d_in[0];
    const float* effmap = (const float*)d_in[1];
    const float* lors   = (const float*)d_in[2];
    float* out = (float*)d_out;
    const int n = in_sizes[2] / 7;

    // ws layout (256-aligned regions)
    char* ws = (char*)d_ws;
    const size_t binh_off   = 0;                               // 512*4
    const size_t binc_off   = 2048;                            // 512*4
    const size_t hist_off   = 4096;                            // NB*4 = 256000
    const size_t offs_off   = hist_off + 256256;               // (NB+1)*4
    const size_t cursor_off = offs_off + 256256;               // NB*4
    const size_t blksum_off = cursor_off + 256256;             // 126*4
    const size_t p_off      = blksum_off + 512;
    const size_t win_off    = p_off    + (((size_t)n * 4 + 255) & ~(size_t)255);
    const size_t binidx_off = win_off  + (((size_t)n * 4 + 255) & ~(size_t)255);
    const size_t lortab_off = binidx_off + (((size_t)n * 4 + 255) & ~(size_t)255);
    const size_t items_off  = lortab_off + (size_t)n * sizeof(LorT);
    const size_t total      = items_off + (size_t)ITEM_CAP * 4;

    hipMemsetAsync(out, 0, (size_t)NVOX * sizeof(float), stream);

    if (ws_size >= total && n < (1 << 17)) {
        int*      binh   = (int*)(ws + binh_off);
        int*      binc   = (int*)(ws + binc_off);
        int*      hist   = (int*)(ws + hist_off);
        int*      offs   = (int*)(ws + offs_off);
        int*      cursor = (int*)(ws + cursor_off);
        int*      blksum = (int*)(ws + blksum_off);
        float*    p      = (float*)(ws + p_off);
        int*      win    = (int*)(ws + win_off);
        int*      binidx = (int*)(ws + binidx_off);
        LorT*     lortab = (LorT*)(ws + lortab_off);
        unsigned* items  = (unsigned*)(ws + items_off);

        // zero binh + hist in one shot
        hipMemsetAsync(ws, 0, hist_off + 256256, stream);

        const int tb = (n + 255) / 256;
        bin_count_kernel<<<tb, 256, 0, stream>>>(lors, binh, binidx, n);
        bin_scan_kernel<<<1, 512, 0, stream>>>(binh, binc);
        reorder_kernel<<<tb, 256, 0, stream>>>(lors, binidx, binc, lortab, n);

        const int chunk = (n + 7) / 8;
        const int Bc = (chunk + 3) / 4;          // 4 waves/block
        forward_count_kernel<<<8 * Bc, 256, 0, stream>>>(
            image, lortab, p, win, hist, n, chunk);
        scanA_kernel<<<125, 512, 0, stream>>>(hist, offs, blksum);
        scanB_kernel<<<1, 128, 0, stream>>>(blksum);
        scanC_kernel<<<125, 512, 0, stream>>>(offs, cursor, blksum);
        emit_fill_kernel<<<8 * Bc, 256, 0, stream>>>(
            lortab, win, cursor, items, n, chunk);
        tileB_kernel<<<NTILES, 256, 0, stream>>>(
            image, effmap, lortab, offs, items, p, out);
    } else {
        trace_direct_kernel<<<(n + 3) / 4, 256, 0, stream>>>(image, lors, out, n);
        const int n4 = NVOX / 4;
        finalize_kernel<<<(n4 + 255) / 256, 256, 0, stream>>>(
            (const float4*)image, (const float4*)effmap, (float4*)out, n4);
    }
}

// Round 11
// 300.035 us; speedup vs baseline: 1.6419x; 1.5510x over previous
//
#include <hip/hip_runtime.h>
#include <math.h>

#define NSTEPS 256
#define GRIDN  160
#define NVOX   (160 * 160 * 160)
#define NTPA   20                  // tiles per axis (8^3-voxel = 16mm tiles)
#define NTILES (NTPA * NTPA * NTPA)
#define NBP    8192                // hist padded to 16*512 for the scan
#define ITEM_CAP (3 * 1024 * 1024)

#define INV_SIGMA 0.05233333f      // 2.355/45 (weight/predicate only)

struct LorT { float4 a; float4 b; };   // a: p0.xyz, tof ; b: d.xyz, L

// ---- strict voxel path (contract OFF: bit-match f32 numpy floor decisions) ----
__device__ __forceinline__ bool sample_vox(
    int j, float p0x, float p0y, float p0z,
    float dx, float dy, float dz, float L, float s_tof,
    int& ix, int& iy, int& iz, float& e)
{
#pragma clang fp contract(off)
    const float t = (j + 0.5f) * (1.0f / 256.0f);
    const float px = p0x + t * dx;
    const float py = p0y + t * dy;
    const float pz = p0z + t * dz;
    const float fx = floorf((px + 160.0f) * 0.5f);
    const float fy = floorf((py + 160.0f) * 0.5f);
    const float fz = floorf((pz + 160.0f) * 0.5f);
    const bool inb = (fx >= 0.0f) & (fx < 160.0f) &
                     (fy >= 0.0f) & (fy < 160.0f) &
                     (fz >= 0.0f) & (fz < 160.0f);
    const float s = (t - 0.5f) * L;
    const float u = (s - s_tof) * INV_SIGMA;
    e = 0.5f * (u * u);
    if (inb & (e < 10.0f)) {
        ix = (int)fx; iy = (int)fy; iz = (int)fz;
        return true;
    }
    return false;
}

__device__ __forceinline__ void lor_window(
    float p0x, float p0y, float p0z, float dx, float dy, float dz,
    float L, float s_tof, int& j0, int& j1)
{
#pragma clang fp contract(off)
    const float SIGMA = (float)(45.0 / 2.355);
    const float CUTS  = 4.4721360f * SIGMA;      // e<10 support
    const float invL = 1.0f / L;
    float t0 = 0.5f + (s_tof - CUTS) * invL;
    float t1 = 0.5f + (s_tof + CUTS) * invL;
    if (t0 > t1) { const float tmp = t0; t0 = t1; t1 = tmp; }
    const float pc[3] = {p0x, p0y, p0z};
    const float dc[3] = {dx, dy, dz};
    #pragma unroll
    for (int a = 0; a < 3; ++a) {
        if (dc[a] != 0.0f) {
            const float inv = 1.0f / dc[a];
            const float ta = (-160.0f - pc[a]) * inv;
            const float tb = ( 160.0f - pc[a]) * inv;
            t0 = fmaxf(t0, fminf(ta, tb));
            t1 = fminf(t1, fmaxf(ta, tb));
        } else if (pc[a] < -160.0f || pc[a] >= 160.0f) t1 = -1.0f;
    }
    t0 = fmaxf(t0, 0.0f);
    t1 = fminf(t1, 1.0f);
    j0 = (int)floorf(t0 * 256.0f - 0.5f) - 2;
    j1 = (int)ceilf (t1 * 256.0f - 0.5f) + 2;
    if (!(t0 <= t1)) { j0 = 0; j1 = -1; }
    j0 = max(j0, 0);
    j1 = min(j1, NSTEPS - 1);
}

// ---- analytic tile-DDA run emission (identical arithmetic in both phases) ----
// Walks the ray's 16mm-tile crossings; per in-box tile emits sample range
// [ja-1, jb+1] (clamped). Padding + exact guards in tileA/B => every sample
// contributes exactly once, in its true tile.
template <int PHASE>
__device__ __forceinline__ void dda_emit(
    int lor, float p0x, float p0y, float p0z,
    float dx, float dy, float dz, float L, float s_tof,
    int* __restrict__ histcur, unsigned* __restrict__ items)
{
#pragma clang fp contract(off)
    int j0, j1;
    lor_window(p0x, p0y, p0z, dx, dy, dz, L, s_tof, j0, j1);
    if (j1 < j0) return;

    const float ts = (j0 + 0.5f) * (1.0f / 256.0f);
    const float te = (j1 + 0.5f) * (1.0f / 256.0f);

    // current (unclamped) tile coords at ts
    int tx = (int)floorf((p0x + ts * dx + 160.0f) * 0.0625f);
    int ty = (int)floorf((p0y + ts * dy + 160.0f) * 0.0625f);
    int tz = (int)floorf((p0z + ts * dz + 160.0f) * 0.0625f);

    float tN[3], dt[3]; int st[3];
    const float pc[3] = {p0x, p0y, p0z};
    const float dc[3] = {dx, dy, dz};
    const int   tc0[3] = {tx, ty, tz};
    #pragma unroll
    for (int a = 0; a < 3; ++a) {
        if (dc[a] > 0.0f) {
            st[a] = 1;
            dt[a] = 16.0f / dc[a];
            tN[a] = ((tc0[a] + 1) * 16.0f - 160.0f - pc[a]) / dc[a];
        } else if (dc[a] < 0.0f) {
            st[a] = -1;
            dt[a] = -16.0f / dc[a];
            tN[a] = (tc0[a] * 16.0f - 160.0f - pc[a]) / dc[a];
        } else {
            st[a] = 0; dt[a] = 0.0f; tN[a] = 1e30f;
        }
    }

    float tcur = ts;
    for (int it = 0; it < 96; ++it) {
        const float tn = fminf(fminf(tN[0], tN[1]), tN[2]);
        const float tseg = fminf(tn, te);
        int ja = (int)ceilf (tcur * 256.0f - 0.5f) - 1;
        int jb = (int)floorf(tseg * 256.0f - 0.5f) + 1;
        ja = max(ja, j0);
        jb = min(jb, j1);
        if (((unsigned)tx < (unsigned)NTPA) & ((unsigned)ty < (unsigned)NTPA) &
            ((unsigned)tz < (unsigned)NTPA) && jb >= ja) {
            const int key = tx * (NTPA * NTPA) + ty * NTPA + tz;
            int js = ja;
            while (js <= jb) {
                const int len = min(jb - js + 1, 64);
                if (PHASE == 0) {
                    atomicAdd(&histcur[key], 1);
                } else {
                    const int slot = atomicAdd(&histcur[key], 1);
                    if (slot < ITEM_CAP)
                        items[slot] = ((unsigned)lor << 14) | ((unsigned)js << 6)
                                    | (unsigned)(len - 1);
                }
                js += len;
            }
        }
        if (tn >= te) break;
        if (tN[0] <= tN[1] && tN[0] <= tN[2]) { tx += st[0]; tN[0] += dt[0]; }
        else if (tN[1] <= tN[2])              { ty += st[1]; tN[1] += dt[1]; }
        else                                  { tz += st[2]; tN[2] += dt[2]; }
        tcur = tn;
    }
}

// ---- prep: 1 thread/LOR — build lortab, zero p, DDA count ----
__global__ __launch_bounds__(256) void prep_kernel(
    const float* __restrict__ lors, LorT* __restrict__ lortab,
    float* __restrict__ p, int* __restrict__ hist, int n)
{
#pragma clang fp contract(off)
    const int i = blockIdx.x * blockDim.x + threadIdx.x;
    if (i >= n) return;
    const float* l = lors + (size_t)i * 7;
    const float p0x = l[0], p0y = l[1], p0z = l[2];
    const float dx = l[3] - p0x, dy = l[4] - p0y, dz = l[5] - p0z;
    const float L = sqrtf(dx * dx + dy * dy + dz * dz);
    lortab[i].a = make_float4(p0x, p0y, p0z, l[6]);
    lortab[i].b = make_float4(dx, dy, dz, L);
    p[i] = 0.0f;
    dda_emit<0>(i, p0x, p0y, p0z, dx, dy, dz, L, l[6] * 0.15f, hist, nullptr);
}

// ---- fill: 1 thread/LOR — DDA emit items ----
__global__ __launch_bounds__(256) void fill_kernel(
    const LorT* __restrict__ lortab, int* __restrict__ cursor,
    unsigned* __restrict__ items, int n)
{
#pragma clang fp contract(off)
    const int i = blockIdx.x * blockDim.x + threadIdx.x;
    if (i >= n) return;
    const float4 A = lortab[i].a, B = lortab[i].b;
    dda_emit<1>(i, A.x, A.y, A.z, B.x, B.y, B.z, B.w, A.w * 0.15f, cursor, items);
}

// ---- hierarchical exclusive scan over NBP=8192 (16 blocks x 512) ----
__global__ __launch_bounds__(512) void scanA_kernel(
    const int* __restrict__ hist, int* __restrict__ offs, int* __restrict__ blksum)
{
    __shared__ int tmp[512];
    const int t = threadIdx.x;
    const int b = blockIdx.x * 512 + t;
    const int v = hist[b];
    tmp[t] = v;
    __syncthreads();
    for (int off = 1; off < 512; off <<= 1) {
        int u = 0;
        if (t >= off) u = tmp[t - off];
        __syncthreads();
        tmp[t] += u;
        __syncthreads();
    }
    offs[b] = tmp[t] - v;
    if (t == 511) blksum[blockIdx.x] = tmp[511];
}

__global__ __launch_bounds__(64) void scanB_kernel(int* __restrict__ blksum)
{
    __shared__ int tmp[16];
    const int t = threadIdx.x;
    if (t < 16) tmp[t] = blksum[t];
    __syncthreads();
    if (t == 0) {
        int run = 0;
        for (int i = 0; i < 16; ++i) { const int v = tmp[i]; tmp[i] = run; run += v; }
        blksum[16] = run;
    }
    __syncthreads();
    if (t < 16) blksum[t] = tmp[t];
}

__global__ __launch_bounds__(512) void scanC_kernel(
    int* __restrict__ offs, int* __restrict__ cursor, const int* __restrict__ blksum)
{
    const int t = threadIdx.x;
    const int b = blockIdx.x * 512 + t;
    const int o = offs[b] + blksum[blockIdx.x];
    offs[b] = o;
    cursor[b] = o;
    if (b == 0) offs[NBP] = blksum[16];
}

// ---- pass A: per-tile forward; image tile in LDS; fast weight ----
__global__ __launch_bounds__(256) void tileA_kernel(
    const float* __restrict__ image, const LorT* __restrict__ lortab,
    const int* __restrict__ offs, const unsigned* __restrict__ items,
    float* __restrict__ p)
{
    const int b = blockIdx.x;
    const int i0 = offs[b], i1 = min(offs[b + 1], ITEM_CAP);
    if (i0 >= i1) return;
    const int tx0 = (b / 400) << 3, ty0 = ((b / 20) % 20) << 3, tz0 = (b % 20) << 3;
    __shared__ float img[512];
    const int t = threadIdx.x;
    for (int v = t; v < 512; v += 256) {
        const int lx = v >> 6, ly = (v >> 3) & 7, lz = v & 7;
        img[v] = image[(size_t)(tx0 + lx) * 25600 + (ty0 + ly) * 160 + (tz0 + lz)];
    }
    __syncthreads();
    for (int idx = i0 + t; idx < i1; idx += 256) {
        const unsigned it = items[idx];
        const int lor = (int)(it >> 14);
        const int js  = (int)((it >> 6) & 255);
        const int len = (int)(it & 63) + 1;
        const float4 A = lortab[lor].a, B = lortab[lor].b;
        const float dl = B.w * (1.0f / 256.0f);
        const float s_tof = A.w * 0.15f;
        float pp = 0.0f;
        for (int m = 0; m < len; ++m) {
            int ix, iy, iz; float e;
            if (sample_vox(js + m, A.x, A.y, A.z, B.x, B.y, B.z, B.w, s_tof,
                           ix, iy, iz, e)) {
                const int lx = ix - tx0, ly = iy - ty0, lz = iz - tz0;
                if ((unsigned)lx < 8u && (unsigned)ly < 8u && (unsigned)lz < 8u)
                    pp += img[(lx << 6) | (ly << 3) | lz] * (__expf(-e) * dl);
            }
        }
        if (pp != 0.0f) atomicAdd(&p[lor], pp);
    }
}

// ---- pass B (fused finalize): LDS bp tile, out = image/(eff+eps)*bp ----
__global__ __launch_bounds__(256) void tileB_kernel(
    const float* __restrict__ image, const float* __restrict__ effmap,
    const LorT* __restrict__ lortab, const int* __restrict__ offs,
    const unsigned* __restrict__ items, const float* __restrict__ p,
    float* __restrict__ out)
{
    const int b = blockIdx.x;
    const int i0 = offs[b], i1 = min(offs[b + 1], ITEM_CAP);
    if (i0 >= i1) return;                 // uncovered tile: out stays 0 (memset)
    const int tx0 = (b / 400) << 3, ty0 = ((b / 20) % 20) << 3, tz0 = (b % 20) << 3;
    __shared__ float acc[512];
    const int t = threadIdx.x;
    for (int v = t; v < 512; v += 256) acc[v] = 0.0f;
    __syncthreads();
    for (int idx = i0 + t; idx < i1; idx += 256) {
        const unsigned it = items[idx];
        const int lor = (int)(it >> 14);
        const int js  = (int)((it >> 6) & 255);
        const int len = (int)(it & 63) + 1;
        const float4 A = lortab[lor].a, B = lortab[lor].b;
        const float dl = B.w * (1.0f / 256.0f);
        const float s_tof = A.w * 0.15f;
        const float pv = p[lor];
        for (int m = 0; m < len; ++m) {
            int ix, iy, iz; float e;
            if (sample_vox(js + m, A.x, A.y, A.z, B.x, B.y, B.z, B.w, s_tof,
                           ix, iy, iz, e)) {
                const int lx = ix - tx0, ly = iy - ty0, lz = iz - tz0;
                if ((unsigned)lx < 8u && (unsigned)ly < 8u && (unsigned)lz < 8u)
                    atomicAdd(&acc[(lx << 6) | (ly << 3) | lz],
                              pv * (__expf(-e) * dl));
            }
        }
    }
    __syncthreads();
    for (int v = t; v < 512; v += 256) {
        const int lx = v >> 6, ly = (v >> 3) & 7, lz = v & 7;
        const size_t g = (size_t)(tx0 + lx) * 25600 + (ty0 + ly) * 160 + (tz0 + lz);
        out[g] = image[g] / (effmap[g] + 1e-8f) * acc[v];
    }
}

// ---- fallback: direct trace with global atomics + separate finalize ----
__global__ __launch_bounds__(256) void trace_direct_kernel(
    const float* __restrict__ image, const float* __restrict__ lors,
    float* __restrict__ bp, int n_lors)
{
#pragma clang fp contract(off)
    const int wave = (int)((blockIdx.x * blockDim.x + threadIdx.x) >> 6);
    const int lane = threadIdx.x & 63;
    if (wave >= n_lors) return;
    const float* l = lors + (size_t)wave * 7;
    const float p0x = l[0], p0y = l[1], p0z = l[2];
    const float dx = l[3] - p0x, dy = l[4] - p0y, dz = l[5] - p0z;
    const float tof = l[6];
    const float L  = sqrtf(dx * dx + dy * dy + dz * dz);
    const float dl = L * (1.0f / 256.0f);
    const float s_tof = tof * 0.15f;
    int j0, j1;
    lor_window(p0x, p0y, p0z, dx, dy, dz, L, s_tof, j0, j1);
    const int nk = (j1 - j0 + 64) >> 6;
    if (nk <= 0) return;
    int flat[4]; float w[4]; float psum = 0.0f;
    for (int k = 0; k < nk; ++k) {
        const int j = j0 + lane + (k << 6);
        int ix, iy, iz; float e; float wk = 0.0f; int fl = 0;
        if (j <= j1 &&
            sample_vox(j, p0x, p0y, p0z, dx, dy, dz, L, s_tof, ix, iy, iz, e)) {
            wk = __expf(-e) * dl;
            fl = ix * 25600 + iy * 160 + iz;
            psum += image[fl] * wk;
        }
        flat[k] = fl; w[k] = wk;
    }
    #pragma unroll
    for (int off = 32; off >= 1; off >>= 1) psum += __shfl_xor(psum, off, 64);
    for (int k = 0; k < nk; ++k)
        if (w[k] > 0.0f) atomicAdd(&bp[flat[k]], psum * w[k]);
}

__global__ __launch_bounds__(256) void finalize_kernel(
    const float4* __restrict__ image, const float4* __restrict__ effmap,
    float4* __restrict__ out, int n4)
{
    const int i = blockIdx.x * blockDim.x + threadIdx.x;
    if (i >= n4) return;
    const float4 im = image[i];
    const float4 ef = effmap[i];
    float4 b = out[i];
    b.x = im.x / (ef.x + 1e-8f) * b.x;
    b.y = im.y / (ef.y + 1e-8f) * b.y;
    b.z = im.z / (ef.z + 1e-8f) * b.z;
    b.w = im.w / (ef.w + 1e-8f) * b.w;
    out[i] = b;
}

extern "C" void kernel_launch(void* const* d_in, const int* in_sizes, int n_in,
                              void* d_out, int out_size, void* d_ws, size_t ws_size,
                              hipStream_t stream) {
    const float* image  = (const float*)d_in[0];
    const float* effmap = (const float*)d_in[1];
    const float* lors   = (const float*)d_in[2];
    float* out = (float*)d_out;
    const int n = in_sizes[2] / 7;

    // ws layout (256-aligned regions)
    char* ws = (char*)d_ws;
    const size_t hist_off   = 0;                               // NBP*4 = 32768
    const size_t offs_off   = hist_off + 32768;                // (NBP+1)*4 -> 33024
    const size_t cursor_off = offs_off + 33024;                // NBP*4
    const size_t blksum_off = cursor_off + 32768;              // 17*4 -> 256
    const size_t p_off      = blksum_off + 256;
    const size_t lortab_off = p_off + (((size_t)n * 4 + 255) & ~(size_t)255);
    const size_t items_off  = lortab_off + (size_t)n * sizeof(LorT);
    const size_t total      = items_off + (size_t)ITEM_CAP * 4;

    hipMemsetAsync(out, 0, (size_t)NVOX * sizeof(float), stream);

    if (ws_size >= total && n < (1 << 17)) {
        int*      hist   = (int*)(ws + hist_off);
        int*      offs   = (int*)(ws + offs_off);
        int*      cursor = (int*)(ws + cursor_off);
        int*      blksum = (int*)(ws + blksum_off);
        float*    p      = (float*)(ws + p_off);
        LorT*     lortab = (LorT*)(ws + lortab_off);
        unsigned* items  = (unsigned*)(ws + items_off);

        hipMemsetAsync(hist, 0, NBP * sizeof(int), stream);

        const int tb = (n + 255) / 256;
        prep_kernel<<<tb, 256, 0, stream>>>(lors, lortab, p, hist, n);
        scanA_kernel<<<16, 512, 0, stream>>>(hist, offs, blksum);
        scanB_kernel<<<1, 64, 0, stream>>>(blksum);
        scanC_kernel<<<16, 512, 0, stream>>>(offs, cursor, blksum);
        fill_kernel<<<tb, 256, 0, stream>>>(lortab, cursor, items, n);
        tileA_kernel<<<NTILES, 256, 0, stream>>>(image, lortab, offs, items, p);
        tileB_kernel<<<NTILES, 256, 0, stream>>>(image, effmap, lortab, offs, items,
                                                 p, out);
    } else {
        trace_direct_kernel<<<(n + 3) / 4, 256, 0, stream>>>(image, lors, out, n);
        const int n4 = NVOX / 4;
        finalize_kernel<<<(n4 + 255) / 256, 256, 0, stream>>>(
            (const float4*)image, (const float4*)effmap, (float4*)out, n4);
    }
}